// Round 16
// baseline (452.901 us; speedup 1.0000x reference)
//
#include <hip/hip_runtime.h>
#include <cstdint>
#include <cstddef>

// ---- problem constants ----
#define N_    16
#define C_    16
#define T_    300
#define V_    25
#define D_    400
#define H_    2
#define DH_   200
#define FF_   1600
#define L_    9
#define W_    291
#define NW_   (N_*W_)      // 4656
#define NT_   (N_*T_)      // 4800

#define KP_   416          // K-pad of D for staging (mult of 32); B zero-padded
#define SD_   400          // tight row stride of D-wide intermediates
#define SQKV_ 1200         // tight qkv row stride
#define SFF_  1600         // tight ffc row stride

// fixed workspace head (bytes)
#define WIN_OFF   0u           // w_in_b  [1280][416]
#define WOUT_OFF  1064960u     // w_out_b [512][416]
#define W1_OFF    1490944u     // w1_b    [1664][416]
#define W2_OFF    2875392u     // w2_b    [512][1600]
#define XS_OFF    4513792u     // xs      [4864][400]
#define QKV_OFF   8404992u     // qkv     [4864][1200]
#define ACC_OFF   20078592u    // acc fp32[4800][400]
#define HEAD_END  27758592u

// s_waitcnt immediates (gfx9): vmcnt[3:0] | expcnt<<4 | lgkmcnt<<8 | vmcnt[5:4]<<14
#define WAIT_VM4   0xF74
#define WAIT_VM0   0xF70
#define WAIT_LGKM0 0xC07F

using u16 = unsigned short;
using u32 = unsigned int;
using frag  = __attribute__((ext_vector_type(8))) short;   // 8 bf16
using f32x4 = __attribute__((ext_vector_type(4))) float;

__device__ __forceinline__ float bf2f(u16 u){
  return __uint_as_float(((u32)u) << 16);
}
__device__ __forceinline__ u16 f2bf(float f){
  return (u16)((__float_as_uint(f) + 0x8000u) >> 16);   // round-half-up
}
// gelu: tanh-form with Pade(3,2) tanh, clamped (1 transcendental: v_rcp)
__device__ __forceinline__ float gelu_f(float v){
  float v2  = v * v;
  float u   = v * (0.7978845608f + 0.03567740814f * v2);
  float u2  = u * u;
  float num = u * (27.f + u2);
  float den = 27.f + 9.f * u2;
  float th  = num * __builtin_amdgcn_rcpf(den);
  th = fminf(fmaxf(th, -1.f), 1.f);
  return 0.5f * v * (1.f + th);
}
__device__ __forceinline__ void unpack8(uint4 v, float* o){
  o[0] = bf2f((u16)(v.x & 0xffffu)); o[1] = bf2f((u16)(v.x >> 16));
  o[2] = bf2f((u16)(v.y & 0xffffu)); o[3] = bf2f((u16)(v.y >> 16));
  o[4] = bf2f((u16)(v.z & 0xffffu)); o[5] = bf2f((u16)(v.z >> 16));
  o[6] = bf2f((u16)(v.w & 0xffffu)); o[7] = bf2f((u16)(v.w >> 16));
}

__device__ __forceinline__ void convw_body(const float* src, u16* dst,
                                           int dN, int dK, int sN, int sK, int idx){
  if (idx >= dN * dK) return;
  int n = idx / dK, k = idx % dK;
  dst[idx] = (n < sN && k < sK) ? f2bf(src[(size_t)n * sK + k]) : (u16)0;
}

// ---- mega-prep: zero acc | embed | 4x weight conversions, one launch ----
#define PREP_GRID 23816
__global__ __launch_bounds__(256) void prep_kernel(const float* __restrict__ x,
                                                   const float* __restrict__ pe,
                                                   const float* __restrict__ w_in,
                                                   const float* __restrict__ w_out,
                                                   const float* __restrict__ w1,
                                                   const float* __restrict__ w2,
                                                   u16* __restrict__ xs,
                                                   u16* __restrict__ w_in_b,
                                                   u16* __restrict__ w_out_b,
                                                   u16* __restrict__ w1_b,
                                                   u16* __restrict__ w2_b,
                                                   float* __restrict__ acc){
  int b = blockIdx.x;
  int tid = threadIdx.x;
  if (b < 7500){
    int idx = b * 256 + tid;
    if (idx < NT_ * D_) acc[idx] = 0.f;
  } else if (b < 15000){
    int idx = (b - 7500) * 256 + tid;
    if (idx < NT_ * D_){
      int d  = idx % D_;
      int nt = idx / D_;
      int t  = nt % T_;
      int n  = nt / T_;
      float val = x[(((size_t)(n*C_ + (d & 15)))*T_ + t)*V_ + (d >> 4)] + pe[t*D_ + d];
      xs[idx] = f2bf(val);
    }
  } else if (b < 17080){
    convw_body(w_in,  w_in_b,  1280, KP_, 1200, D_,  (b - 15000) * 256 + tid);
  } else if (b < 17912){
    convw_body(w_out, w_out_b,  512, KP_,  400, D_,  (b - 17080) * 256 + tid);
  } else if (b < 20616){
    convw_body(w1,    w1_b,   1664, KP_, 1600, D_,  (b - 17912) * 256 + tid);
  } else {
    convw_body(w2,    w2_b,    512, SFF_, 400, FF_, (b - 20616) * 256 + tid);
  }
}

// ---- MFMA GEMM: shared 128x128 tile, register-FIFO pipeline (distance 3):
//      stages prefetched to VGPRs (2 rotating slots, unroll-2 loop so indices
//      are literals), ds-written into 2-buffer LDS (32 KB). Per-wave vmcnt(4)
//      waits (never 0 mid-loop). Epilogue stride-72 LDS -> dwordx4 stores. ----
template<int ACT>
__global__ __launch_bounds__(256, 3) void gemm_mfma(const u16* __restrict__ A, int lda,
                                                    const u16* __restrict__ B, int ldb,
                                                    const float* __restrict__ bias,
                                                    u16* __restrict__ C, int ldc,
                                                    int Nn, int KPd,
                                                    int gx, int gy){
  __shared__ u16 smem[18432];              // 36KB: A buf0/1 @0/4096, B @8192/12288; ep tail
  int id = blockIdx.x;
  int c  = id & 7, t = id >> 3;
  int bx = t % gx;
  int by = (t / gx) * 8 + c;               // XCD c owns M-tile residue class
  if (by >= gy) return;
  const int m0 = by * 128, n0 = bx * 128;

  const int tid  = threadIdx.x;
  const int lane = tid & 63;
  const int wv   = tid >> 6;
  const int quad = lane >> 4, l16 = lane & 15;
  const int wm   = wv & 1,   wn  = wv >> 1;

  const int rl   = lane >> 2;
  const int sseg = (lane & 3) ^ ((lane >> 3) & 3);     // xor-swizzled k-segment
  const u16* Ag = A + (size_t)(m0 + wv*32 + rl) * lda + sseg*8;
  const u16* Bg = B + (size_t)(n0 + wv*32 + rl) * ldb + sseg*8;
  const size_t a16 = (size_t)16 * lda, b16 = (size_t)16 * ldb;
  const int wofs = (wv*32 + rl)*32 + (lane & 3)*8;     // u16 offset within a stage

  uint4 ra0h0, ra0h1, rb0h0, rb0h1;        // slot 0
  uint4 ra1h0, ra1h1, rb1h0, rb1h1;        // slot 1

  f32x4 acc[4][4] = {};
  const int sa = quad ^ ((l16 >> 1) & 3);              // read-side slot

  auto load0 = [&](int kt){
    ra0h0 = *(const uint4*)(Ag + kt);
    ra0h1 = *(const uint4*)(Ag + kt + a16);
    rb0h0 = *(const uint4*)(Bg + kt);
    rb0h1 = *(const uint4*)(Bg + kt + b16);
  };
  auto load1 = [&](int kt){
    ra1h0 = *(const uint4*)(Ag + kt);
    ra1h1 = *(const uint4*)(Ag + kt + a16);
    rb1h0 = *(const uint4*)(Bg + kt);
    rb1h1 = *(const uint4*)(Bg + kt + b16);
  };
  auto wstage0 = [&](int buf){
    *(uint4*)(&smem[buf*4096 + wofs])              = ra0h0;
    *(uint4*)(&smem[buf*4096 + 512 + wofs])        = ra0h1;   // 16*32 = 512
    *(uint4*)(&smem[8192 + buf*4096 + wofs])       = rb0h0;
    *(uint4*)(&smem[8192 + buf*4096 + 512 + wofs]) = rb0h1;
  };
  auto wstage1 = [&](int buf){
    *(uint4*)(&smem[buf*4096 + wofs])              = ra1h0;
    *(uint4*)(&smem[buf*4096 + 512 + wofs])        = ra1h1;
    *(uint4*)(&smem[8192 + buf*4096 + wofs])       = rb1h0;
    *(uint4*)(&smem[8192 + buf*4096 + 512 + wofs]) = rb1h1;
  };
  auto compute = [&](int buf){
    const u16* Ar = &smem[buf*4096];
    const u16* Br = &smem[8192 + buf*4096];
    frag af[4], bfr[4];
    #pragma unroll
    for (int i = 0; i < 4; ++i){
      af[i]  = *(const frag*)(&Ar[(wm*64 + i*16 + l16)*32 + sa*8]);
      bfr[i] = *(const frag*)(&Br[(wn*64 + i*16 + l16)*32 + sa*8]);
    }
    #pragma unroll
    for (int i = 0; i < 4; ++i)
      #pragma unroll
      for (int j = 0; j < 4; ++j)
        acc[i][j] = __builtin_amdgcn_mfma_f32_16x16x32_bf16(af[i], bfr[j], acc[i][j], 0, 0, 0);
  };

  const int nit = KPd >> 5;                // 13 or 50
  // prologue: stage0 -> slot0, stage1 -> slot1, write stage0, load stage2 -> slot0
  load0(0);
  if (nit > 1) load1(32);
  if (nit > 1) __builtin_amdgcn_s_waitcnt(WAIT_VM4);
  else         __builtin_amdgcn_s_waitcnt(WAIT_VM0);
  wstage0(0);
  if (nit > 2) load0(64);
  __builtin_amdgcn_s_waitcnt(WAIT_LGKM0);
  __builtin_amdgcn_s_barrier();

  for (int it = 0; it < nit; it += 2){
    // even phase: compute stage it (buf0); stage it+1 (slot1) -> buf1
    if (it + 1 < nit){
      if (it + 2 < nit) __builtin_amdgcn_s_waitcnt(WAIT_VM4);
      else              __builtin_amdgcn_s_waitcnt(WAIT_VM0);
      wstage1(1);
      if (it + 3 < nit) load1((it + 3) << 5);
    }
    compute(0);
    __builtin_amdgcn_s_waitcnt(WAIT_LGKM0);
    __builtin_amdgcn_s_barrier();
    // odd phase: compute stage it+1 (buf1); stage it+2 (slot0) -> buf0
    if (it + 1 < nit){
      if (it + 2 < nit){
        if (it + 3 < nit) __builtin_amdgcn_s_waitcnt(WAIT_VM4);
        else              __builtin_amdgcn_s_waitcnt(WAIT_VM0);
        wstage0(0);
        if (it + 4 < nit) load0((it + 4) << 5);
      }
      compute(1);
      __builtin_amdgcn_s_waitcnt(WAIT_LGKM0);
      __builtin_amdgcn_s_barrier();
    }
  }

  // epilogue: wave-private stride-72 tile -> coalesced dwordx4 stores
  u16* ep = &smem[wv * 4608];              // 4*4608 = 18432 <= smem size
  #pragma unroll
  for (int j = 0; j < 4; ++j){
    int n = n0 + wn*64 + j*16 + l16;
    float bj = (n < Nn) ? bias[n] : 0.f;
    #pragma unroll
    for (int i = 0; i < 4; ++i){
      #pragma unroll
      for (int r = 0; r < 4; ++r){
        float v = acc[i][j][r] + bj;
        if (ACT) v = gelu_f(v);
        ep[(i*16 + quad*4 + r)*72 + j*16 + l16] = f2bf(v);
      }
    }
  }
  #pragma unroll
  for (int p = 0; p < 8; ++p){
    int row = p*8 + (lane >> 3);
    int seg = lane & 7;
    int nc  = n0 + wn*64 + seg*8;
    if (nc < Nn){                           // Nn multiple of 8 -> seg-exact
      uint4 v = *(const uint4*)(&ep[row*72 + seg*8]);
      *(uint4*)(C + (size_t)(m0 + wm*64 + row)*ldc + nc) = v;
    }
  }
}

// ---- attention for one chunk of windows; 16B vectorized staging ----
__global__ __launch_bounds__(256) void attn_kernel(const u16* __restrict__ qkv,
                                                   u16* __restrict__ o,
                                                   int g0){
  __shared__ float sq[L_ * 1200];
  __shared__ float sc[H_ * L_ * L_];
  __shared__ float att[H_ * L_ * L_];
  const int g = g0 + blockIdx.x;
  const int n = g / W_, w = g % W_;
  const int tid = threadIdx.x;

  for (int i = tid; i < L_ * 150; i += 256){
    int l = i / 150, ck = i % 150;
    uint4 v = *(const uint4*)(qkv + ((size_t)(n*T_ + w + l)) * SQKV_ + ck*8);
    unpack8(v, &sq[l*1200 + ck*8]);
  }
  __syncthreads();

  if (tid < H_ * L_ * L_){
    int h = tid / (L_*L_), rem = tid % (L_*L_), qi = rem / L_, ki = rem % L_;
    const float* qp = &sq[qi*1200 + h*DH_];
    const float* kp = &sq[ki*1200 + D_ + h*DH_];
    float s = 0.f;
    for (int dd = 0; dd < DH_; ++dd) s += qp[dd] * kp[dd];
    sc[tid] = s * 0.07071067811865475f;  // 1/sqrt(200)
  }
  __syncthreads();

  if (tid < H_ * L_){
    int base = tid * L_;
    float mx = -1e30f;
    for (int j = 0; j < L_; ++j) mx = fmaxf(mx, sc[base + j]);
    float sum = 0.f;
    for (int j = 0; j < L_; ++j){ float e = __expf(sc[base + j] - mx); att[base + j] = e; sum += e; }
    float inv = 1.f / sum;
    for (int j = 0; j < L_; ++j) att[base + j] *= inv;
  }
  __syncthreads();

  for (int i = tid; i < L_ * D_; i += 256){
    int l = i / D_, d = i % D_;
    int h = d / DH_;
    float a = 0.f;
    #pragma unroll
    for (int ki = 0; ki < L_; ++ki)
      a += att[h*(L_*L_) + l*L_ + ki] * sq[ki*1200 + 2*D_ + d];
    o[((size_t)blockIdx.x * L_ + l) * SD_ + d] = f2bf(a);
  }
}

// ---- LN1: h = LN(xs_window + y), wave-per-row ----
__global__ __launch_bounds__(256) void ln1_kernel(const u16* __restrict__ y,
                                                  const float* __restrict__ gam,
                                                  const float* __restrict__ bet,
                                                  u16* __restrict__ out,
                                                  const u16* __restrict__ xs,
                                                  int g0){
  const int wv = threadIdx.x >> 6, lane = threadIdx.x & 63;
  const int r = blockIdx.x * 4 + wv;
  const int g = g0 + r / L_, l = r % L_;
  const int n = g / W_, w = g % W_;
  const u16* arow = xs + ((size_t)(n*T_ + w + l)) * SD_;
  const u16* brow = y + (size_t)r * SD_;

  const bool act = lane < 50;
  float v[8];
  float s = 0.f, s2 = 0.f;
  if (act){
    float a8[8], b8[8];
    unpack8(*(const uint4*)(arow + lane*8), a8);
    unpack8(*(const uint4*)(brow + lane*8), b8);
    #pragma unroll
    for (int i = 0; i < 8; ++i){ v[i] = a8[i] + b8[i]; s += v[i]; s2 += v[i]*v[i]; }
  } else {
    #pragma unroll
    for (int i = 0; i < 8; ++i) v[i] = 0.f;
  }
  #pragma unroll
  for (int off = 32; off; off >>= 1){
    s  += __shfl_xor(s,  off);
    s2 += __shfl_xor(s2, off);
  }
  float mean = s * (1.f / D_);
  float rstd = rsqrtf(s2 * (1.f / D_) - mean*mean + 1e-5f);
  if (act){
    float4 ga = *(const float4*)(gam + lane*8);
    float4 gb = *(const float4*)(gam + lane*8 + 4);
    float4 ba = *(const float4*)(bet + lane*8);
    float4 bb = *(const float4*)(bet + lane*8 + 4);
    float gg[8] = {ga.x,ga.y,ga.z,ga.w, gb.x,gb.y,gb.z,gb.w};
    float bb8[8]= {ba.x,ba.y,ba.z,ba.w, bb.x,bb.y,bb.z,bb.w};
    u32 o4[4];
    #pragma unroll
    for (int i = 0; i < 4; ++i){
      u16 lo = f2bf((v[2*i]   - mean) * rstd * gg[2*i]   + bb8[2*i]);
      u16 hi = f2bf((v[2*i+1] - mean) * rstd * gg[2*i+1] + bb8[2*i+1]);
      o4[i] = (u32)lo | ((u32)hi << 16);
    }
    *(uint4*)(out + (size_t)r * SD_ + lane*8) = make_uint4(o4[0],o4[1],o4[2],o4[3]);
  }
}

// ---- LN2 + scatter fused, coalesced atomics via LDS row buffer ----
__global__ __launch_bounds__(256) void ln2_scatter_kernel(const u16* __restrict__ h,
                                                          const u16* __restrict__ y,
                                                          const float* __restrict__ gam,
                                                          const float* __restrict__ bet,
                                                          float* __restrict__ acc,
                                                          int g0){
  __shared__ float buf[4][400];
  const int wv = threadIdx.x >> 6, lane = threadIdx.x & 63;
  const int tid = threadIdx.x;
  const int r0 = blockIdx.x * 4;
  {
    const int r = r0 + wv;
    const u16* arow = h + (size_t)r * SD_;
    const u16* brow = y + (size_t)r * SD_;
    const bool act = lane < 50;
    float v[8];
    float s = 0.f, s2 = 0.f;
    if (act){
      float a8[8], b8[8];
      unpack8(*(const uint4*)(arow + lane*8), a8);
      unpack8(*(const uint4*)(brow + lane*8), b8);
      #pragma unroll
      for (int i = 0; i < 8; ++i){ v[i] = a8[i] + b8[i]; s += v[i]; s2 += v[i]*v[i]; }
    } else {
      #pragma unroll
      for (int i = 0; i < 8; ++i) v[i] = 0.f;
    }
    #pragma unroll
    for (int off = 32; off; off >>= 1){
      s  += __shfl_xor(s,  off);
      s2 += __shfl_xor(s2, off);
    }
    float mean = s * (1.f / D_);
    float rstd = rsqrtf(s2 * (1.f / D_) - mean*mean + 1e-5f);
    if (act){
      float4 ga = *(const float4*)(gam + lane*8);
      float4 gb = *(const float4*)(gam + lane*8 + 4);
      float4 ba = *(const float4*)(bet + lane*8);
      float4 bb = *(const float4*)(bet + lane*8 + 4);
      float gg[8] = {ga.x,ga.y,ga.z,ga.w, gb.x,gb.y,gb.z,gb.w};
      float bb8[8]= {ba.x,ba.y,ba.z,ba.w, bb.x,bb.y,bb.z,bb.w};
      #pragma unroll
      for (int i = 0; i < 8; ++i)
        buf[wv][lane*8 + i] = (v[i] - mean) * rstd * gg[i] + bb8[i];
    }
  }
  __syncthreads();
  #pragma unroll
  for (int rr = 0; rr < 4; ++rr){
    int r = r0 + rr;
    int g = g0 + r / L_, l = r % L_;
    int n = g / W_, w = g % W_;
    size_t base = ((size_t)(n*T_ + (w >> 1) + l)) * D_;
    atomicAdd(acc + base + tid, buf[rr][tid]);
    if (tid + 256 < D_) atomicAdd(acc + base + tid + 256, buf[rr][tid + 256]);
  }
}

// ---- acc[n,t,d] -> out[n,c,t,v] fp32 ----
__global__ __launch_bounds__(256) void final_kernel(const float* __restrict__ acc,
                                                    float* __restrict__ dout){
  int idx = blockIdx.x * 256 + threadIdx.x;
  if (idx >= NT_ * D_) return;
  int d  = idx % D_;
  int nt = idx / D_;
  int t  = nt % T_;
  int n  = nt / T_;
  dout[(((size_t)(n*C_ + (d & 15)))*T_ + t)*V_ + (d >> 4)] = acc[idx];
}

extern "C" void kernel_launch(void* const* d_in, const int* in_sizes, int n_in,
                              void* d_out, int out_size, void* d_ws, size_t ws_size,
                              hipStream_t stream){
  (void)in_sizes; (void)n_in; (void)out_size;
  const float* x     = (const float*)d_in[0];
  const float* pe    = (const float*)d_in[1];
  const float* w_in  = (const float*)d_in[2];
  const float* b_in  = (const float*)d_in[3];
  const float* w_out = (const float*)d_in[4];
  const float* b_out = (const float*)d_in[5];
  const float* w1    = (const float*)d_in[6];
  const float* b1    = (const float*)d_in[7];
  const float* w2    = (const float*)d_in[8];
  const float* b2    = (const float*)d_in[9];
  const float* ln1g  = (const float*)d_in[10];
  const float* ln1b  = (const float*)d_in[11];
  const float* ln2g  = (const float*)d_in[12];
  const float* ln2b  = (const float*)d_in[13];

  // ws_size-adaptive chunk count (deterministic -> graph-safe)
  int nch = 3;
  {
    size_t need1 = (size_t)HEAD_END + (size_t)41984 * 5600;   // 1 chunk
    size_t need2 = (size_t)HEAD_END + (size_t)20992 * 5600;   // 2 chunks
    if (ws_size >= need1 + (1u<<20)) nch = 1;
    else if (ws_size >= need2 + (1u<<20)) nch = 2;
  }
  const int CW  = NW_ / nch;
  const int RC  = CW * L_;
  const int RCP = ((RC + 127) / 128) * 128;

  char* ws = (char*)d_ws;
  u16*   w_in_b  = (u16*)(ws + WIN_OFF);
  u16*   w_out_b = (u16*)(ws + WOUT_OFF);
  u16*   w1_b    = (u16*)(ws + W1_OFF);
  u16*   w2_b    = (u16*)(ws + W2_OFF);
  u16*   xs      = (u16*)(ws + XS_OFF);
  u16*   qkv     = (u16*)(ws + QKV_OFF);
  float* acc     = (float*)(ws + ACC_OFF);
  u16*   o_c     = (u16*)(ws + HEAD_END);
  u16*   y_c     = o_c + (size_t)RCP * SD_;
  u16*   h_c     = y_c + (size_t)RCP * SD_;
  u16*   ffc     = h_c + (size_t)RCP * SD_;

  prep_kernel<<<PREP_GRID, 256, 0, stream>>>(x, pe, w_in, w_out, w1, w2,
                                             xs, w_in_b, w_out_b, w1_b, w2_b, acc);

  // qkv = xs @ w_in^T + b_in   [4800 x 1200]
  {
    int gx = 10, gy = (NT_ + 127)/128, gy8 = (gy + 7) & ~7;
    gemm_mfma<0><<<gx*gy8, 256, 0, stream>>>(
        xs, SD_, w_in_b, KP_, b_in, qkv, SQKV_, 1200, KP_, gx, gy);
  }

  const int gyc = RCP/128, gyc8 = (gyc + 7) & ~7;

  for (int g0 = 0; g0 < NW_; g0 += CW){
    attn_kernel<<<CW, 256, 0, stream>>>(qkv, o_c, g0);

    gemm_mfma<0><<<4*gyc8, 256, 0, stream>>>(
        o_c, SD_, w_out_b, KP_, b_out, y_c, SD_, D_, KP_, 4, gyc);

    ln1_kernel<<<RC/4, 256, 0, stream>>>(y_c, ln1g, ln1b, h_c, xs, g0);

    gemm_mfma<1><<<13*gyc8, 256, 0, stream>>>(
        h_c, SD_, w1_b, KP_, b1, ffc, SFF_, FF_, KP_, 13, gyc);

    gemm_mfma<0><<<4*gyc8, 256, 0, stream>>>(
        ffc, SFF_, w2_b, SFF_, b2, y_c, SD_, D_, SFF_, 4, gyc);

    ln2_scatter_kernel<<<RC/4, 256, 0, stream>>>(h_c, y_c, ln2g, ln2b, acc, g0);
  }

  final_kernel<<<(NT_*D_ + 255)/256, 256, 0, stream>>>(acc, (float*)d_out);
}